// Round 1
// baseline (841.908 us; speedup 1.0000x reference)
//
#include <hip/hip_runtime.h>
#include <math.h>

#define D_MODEL 1024
#define NUM_EXPERTS 8
#define TOPK 2

#define TM 64
#define TN 64
#define TK 32

// ---------------- Gating: one wave (64 lanes) per token ----------------
__global__ __launch_bounds__(64) void moe_gating(
    const float* __restrict__ x,    // [N, D]
    const float* __restrict__ Wg,   // [E, D]
    const float* __restrict__ bg,   // [E]
    int*   __restrict__ eidx,       // [N*2]
    float* __restrict__ ew,         // [N*2]
    int*   __restrict__ counts)     // [E]
{
    const int n    = blockIdx.x;
    const int lane = threadIdx.x;

    const float* xr = x + (size_t)n * D_MODEL;
    float xv[16];
#pragma unroll
    for (int i = 0; i < 16; ++i) xv[i] = xr[lane + 64 * i];

    float logit[NUM_EXPERTS];
#pragma unroll
    for (int e = 0; e < NUM_EXPERTS; ++e) {
        const float* wgr = Wg + e * D_MODEL;
        float p = 0.f;
#pragma unroll
        for (int i = 0; i < 16; ++i) p += xv[i] * wgr[lane + 64 * i];
        // butterfly reduce across 64 lanes (all lanes end with identical sum)
#pragma unroll
        for (int off = 32; off >= 1; off >>= 1) p += __shfl_xor(p, off, 64);
        logit[e] = p + bg[e];
    }

    // stable top-2: strict '>' keeps earliest index on ties (jax.lax.top_k)
    int i0 = 0; float v0 = logit[0];
#pragma unroll
    for (int e = 1; e < NUM_EXPERTS; ++e)
        if (logit[e] > v0) { v0 = logit[e]; i0 = e; }
    int i1 = -1; float v1 = -INFINITY;
#pragma unroll
    for (int e = 0; e < NUM_EXPERTS; ++e) {
        if (e == i0) continue;
        if (logit[e] > v1) { v1 = logit[e]; i1 = e; }
    }

    // softmax over (v0, v1); v0 >= v1 so exp arg <= 0
    float e1 = expf(v1 - v0);
    float inv = 1.f / (1.f + e1);

    if (lane == 0) {
        eidx[2 * n]     = i0;
        eidx[2 * n + 1] = i1;
        ew[2 * n]       = inv;
        ew[2 * n + 1]   = e1 * inv;
        atomicAdd(&counts[i0], 1);
        atomicAdd(&counts[i1], 1);
    }
}

// ---------------- Scan: offsets, cursors, tile bases ----------------
__global__ void moe_scan(const int* __restrict__ counts,
                         int* __restrict__ offsets,   // [E+1]
                         int* __restrict__ cursor,    // [E]
                         int* __restrict__ tileBase,  // [E+1]
                         int* __restrict__ totalTiles)
{
    int off = 0, tb = 0;
    for (int e = 0; e < NUM_EXPERTS; ++e) {
        offsets[e]  = off;
        cursor[e]   = off;
        tileBase[e] = tb;
        tb  += (counts[e] + TM - 1) / TM;
        off += counts[e];
    }
    offsets[NUM_EXPERTS]  = off;
    tileBase[NUM_EXPERTS] = tb;
    *totalTiles = tb;
}

// ---------------- Fill per-expert row lists ----------------
__global__ __launch_bounds__(256) void moe_fill(
    const int*   __restrict__ eidx,
    const float* __restrict__ ew,
    int*   __restrict__ cursor,
    int*   __restrict__ rowTok,
    float* __restrict__ rowW,
    int N)
{
    int n = blockIdx.x * blockDim.x + threadIdx.x;
    if (n >= N) return;
#pragma unroll
    for (int k = 0; k < TOPK; ++k) {
        int e = eidx[2 * n + k];
        int pos = atomicAdd(&cursor[e], 1);
        rowTok[pos] = n;
        rowW[pos]   = ew[2 * n + k];
    }
}

// ---------------- Grouped GEMM: Y = gather(x) @ We[e]^T, scatter-add ----------------
// block: 256 threads; tile 64(M:tokens) x 64(N:out dims) x 32(K)
// thread (tx,ty) computes rows ty*4..ty*4+3, cols tx*4..tx*4+3
__global__ __launch_bounds__(256) void moe_gemm(
    const float* __restrict__ x,        // [N, D]
    const float* __restrict__ We,       // [E, D_out, D_in]
    const float* __restrict__ be,       // [E, D]
    const int*   __restrict__ offsets,  // [E+1]
    const int*   __restrict__ tileBase, // [E+1]
    const int*   __restrict__ totalTiles,
    const int*   __restrict__ rowTok,
    const float* __restrict__ rowW,
    float*       __restrict__ out)      // [N, D]
{
    __shared__ float As[TK][TM + 4];   // k-major; +4 pad keeps 16B align, breaks bank alias
    __shared__ float Bs[TK][TN + 4];
    __shared__ int   tokS[TM];
    __shared__ float wS[TM];

    const int tile = blockIdx.x;
    if (tile >= *totalTiles) return;

    // find owning expert (8-entry linear search)
    int e = 0;
#pragma unroll
    for (int q = 0; q < NUM_EXPERTS; ++q)
        if (tile >= tileBase[q + 1]) e = q + 1;

    const int row0   = offsets[e] + (tile - tileBase[e]) * TM;
    const int rowEnd = offsets[e + 1];
    const int c0     = blockIdx.y * TN;

    const int tid = threadIdx.x;
    const int tx = tid & 15, ty = tid >> 4;
    const int lr = tid >> 2;            // 0..63 : row/col loaded by this thread
    const int lk = (tid & 3) * 8;       // 0,8,16,24 : k-offset loaded

    if (tid < TM) {
        int gr = row0 + tid;
        tokS[tid] = (gr < rowEnd) ? rowTok[gr] : -1;
        wS[tid]   = (gr < rowEnd) ? rowW[gr] : 0.f;
    }
    __syncthreads();

    const int tokL = tokS[lr];
    const float* ax = x + (size_t)(tokL < 0 ? 0 : tokL) * D_MODEL;
    const float* bw = We + ((size_t)e * D_MODEL + c0 + lr) * D_MODEL;

    float acc[4][4];
#pragma unroll
    for (int i = 0; i < 4; ++i)
#pragma unroll
        for (int j = 0; j < 4; ++j) acc[i][j] = 0.f;

    for (int k0 = 0; k0 < D_MODEL; k0 += TK) {
        float4 av0 = *(const float4*)(ax + k0 + lk);
        float4 av1 = *(const float4*)(ax + k0 + lk + 4);
        float4 bv0 = *(const float4*)(bw + k0 + lk);
        float4 bv1 = *(const float4*)(bw + k0 + lk + 4);

        __syncthreads();   // previous iteration's compute done
        As[lk + 0][lr] = av0.x; As[lk + 1][lr] = av0.y;
        As[lk + 2][lr] = av0.z; As[lk + 3][lr] = av0.w;
        As[lk + 4][lr] = av1.x; As[lk + 5][lr] = av1.y;
        As[lk + 6][lr] = av1.z; As[lk + 7][lr] = av1.w;
        Bs[lk + 0][lr] = bv0.x; Bs[lk + 1][lr] = bv0.y;
        Bs[lk + 2][lr] = bv0.z; Bs[lk + 3][lr] = bv0.w;
        Bs[lk + 4][lr] = bv1.x; Bs[lk + 5][lr] = bv1.y;
        Bs[lk + 6][lr] = bv1.z; Bs[lk + 7][lr] = bv1.w;
        __syncthreads();   // tiles visible

#pragma unroll
        for (int kk = 0; kk < TK; ++kk) {
            float4 a = *(const float4*)&As[kk][ty * 4];
            float4 b = *(const float4*)&Bs[kk][tx * 4];
            acc[0][0] += a.x * b.x; acc[0][1] += a.x * b.y;
            acc[0][2] += a.x * b.z; acc[0][3] += a.x * b.w;
            acc[1][0] += a.y * b.x; acc[1][1] += a.y * b.y;
            acc[1][2] += a.y * b.z; acc[1][3] += a.y * b.w;
            acc[2][0] += a.z * b.x; acc[2][1] += a.z * b.y;
            acc[2][2] += a.z * b.z; acc[2][3] += a.z * b.w;
            acc[3][0] += a.w * b.x; acc[3][1] += a.w * b.y;
            acc[3][2] += a.w * b.z; acc[3][3] += a.w * b.w;
        }
    }

    const float* bias = be + (size_t)e * D_MODEL + c0;
#pragma unroll
    for (int i = 0; i < 4; ++i) {
        int r = ty * 4 + i;
        int tok = tokS[r];
        if (tok < 0) continue;
        float w = wS[r];
        float* orow = out + (size_t)tok * D_MODEL + c0;
#pragma unroll
        for (int j = 0; j < 4; ++j) {
            int c = tx * 4 + j;
            atomicAdd(&orow[c], w * (acc[i][j] + bias[c]));
        }
    }
}

// ---------------- Launch ----------------
extern "C" void kernel_launch(void* const* d_in, const int* in_sizes, int n_in,
                              void* d_out, int out_size, void* d_ws, size_t ws_size,
                              hipStream_t stream) {
    const float* x  = (const float*)d_in[0];
    const float* We = (const float*)d_in[1];
    const float* be = (const float*)d_in[2];
    const float* Wg = (const float*)d_in[3];
    const float* bg = (const float*)d_in[4];
    float* out = (float*)d_out;

    const int N = in_sizes[0] / D_MODEL;       // 8192 tokens
    const int R = N * TOPK;                    // 16384 routed rows

    // workspace layout
    char* ws = (char*)d_ws;
    int*   counts     = (int*)ws;              // 8
    int*   offsets    = counts + 8;            // 9
    int*   cursor     = offsets + 9;           // 8
    int*   tileBase   = cursor + 8;            // 9
    int*   totalTiles = tileBase + 9;          // 1
    int*   eidx   = (int*)(ws + 256);          // [2N]
    float* ew     = (float*)(eidx + R);        // [2N]
    int*   rowTok = (int*)(ew + R);            // [2N]
    float* rowW   = (float*)(rowTok + R);      // [2N]

    hipMemsetAsync(counts, 0, 256, stream);
    hipMemsetAsync(out, 0, (size_t)N * D_MODEL * sizeof(float), stream);

    moe_gating<<<N, 64, 0, stream>>>(x, Wg, bg, eidx, ew, counts);
    moe_scan<<<1, 1, 0, stream>>>(counts, offsets, cursor, tileBase, totalTiles);
    moe_fill<<<(N + 255) / 256, 256, 0, stream>>>(eidx, ew, cursor, rowTok, rowW, N);

    const int maxTiles = R / TM + NUM_EXPERTS;  // fixed grid; device-side early-exit
    dim3 grid(maxTiles, D_MODEL / TN);
    moe_gemm<<<grid, 256, 0, stream>>>(x, We, be, offsets, tileBase, totalTiles,
                                       rowTok, rowW, out);
}

// Round 2
// 742.348 us; speedup vs baseline: 1.1341x; 1.1341x over previous
//
#include <hip/hip_runtime.h>
#include <math.h>

#define D_MODEL 1024
#define NUM_EXPERTS 8
#define TOPK 2
#define TM 128
#define TN 128
#define BK 32

typedef __attribute__((ext_vector_type(8))) short short8;
typedef __attribute__((ext_vector_type(4))) float f32x4;

__device__ __forceinline__ unsigned short bf16_rne(float f) {
    unsigned int u = __builtin_bit_cast(unsigned int, f);
    unsigned int r = u + 0x7fffu + ((u >> 16) & 1u);
    return (unsigned short)(r >> 16);
}
__device__ __forceinline__ float bf16f(unsigned short h) {
    unsigned int u = ((unsigned int)h) << 16;
    return __builtin_bit_cast(float, u);
}

// async global->LDS, 16B per lane, dest = wave-uniform base + lane*16
__device__ __forceinline__ void gload_lds16(const unsigned short* g, unsigned short* l) {
    __builtin_amdgcn_global_load_lds(
        (const __attribute__((address_space(1))) unsigned int*)g,
        (__attribute__((address_space(3))) unsigned int*)l, 16, 0, 0);
}

// ---------------- convert We -> hi/lo bf16 planes ----------------
__global__ __launch_bounds__(256) void convert_W(
    const float* __restrict__ W, unsigned short* __restrict__ hi,
    unsigned short* __restrict__ lo, int n4)
{
    int i = blockIdx.x * 256 + threadIdx.x;
    if (i >= n4) return;
    float4 v = ((const float4*)W)[i];
    ushort4 h, l;
    h.x = bf16_rne(v.x); l.x = bf16_rne(v.x - bf16f(h.x));
    h.y = bf16_rne(v.y); l.y = bf16_rne(v.y - bf16f(h.y));
    h.z = bf16_rne(v.z); l.z = bf16_rne(v.z - bf16f(h.z));
    h.w = bf16_rne(v.w); l.w = bf16_rne(v.w - bf16f(h.w));
    ((ushort4*)hi)[i] = h;
    ((ushort4*)lo)[i] = l;
}

// ---------------- fused: convert x -> hi/lo planes + gating top-2 ----------------
// 4 waves/block, one token per wave
__global__ __launch_bounds__(256) void gate_convert_x(
    const float* __restrict__ x, const float* __restrict__ Wg,
    const float* __restrict__ bg,
    unsigned short* __restrict__ xhi, unsigned short* __restrict__ xlo,
    int* __restrict__ eidx, float* __restrict__ ew, int* __restrict__ counts, int N)
{
    const int wave = threadIdx.x >> 6, lane = threadIdx.x & 63;
    const int n = blockIdx.x * 4 + wave;
    if (n >= N) return;

    const float4* xr4 = (const float4*)(x + (size_t)n * D_MODEL);
    float xv[16];
#pragma unroll
    for (int j = 0; j < 4; ++j) {
        float4 v = xr4[j * 64 + lane];
        xv[4 * j + 0] = v.x; xv[4 * j + 1] = v.y;
        xv[4 * j + 2] = v.z; xv[4 * j + 3] = v.w;
        ushort4 h, l;
        h.x = bf16_rne(v.x); l.x = bf16_rne(v.x - bf16f(h.x));
        h.y = bf16_rne(v.y); l.y = bf16_rne(v.y - bf16f(h.y));
        h.z = bf16_rne(v.z); l.z = bf16_rne(v.z - bf16f(h.z));
        h.w = bf16_rne(v.w); l.w = bf16_rne(v.w - bf16f(h.w));
        ((ushort4*)(xhi + (size_t)n * D_MODEL))[j * 64 + lane] = h;
        ((ushort4*)(xlo + (size_t)n * D_MODEL))[j * 64 + lane] = l;
    }

    float logit[NUM_EXPERTS];
#pragma unroll
    for (int e = 0; e < NUM_EXPERTS; ++e) {
        const float4* wg4 = (const float4*)(Wg + (size_t)e * D_MODEL);
        float p = 0.f;
#pragma unroll
        for (int j = 0; j < 4; ++j) {
            float4 w = wg4[j * 64 + lane];
            p += xv[4 * j + 0] * w.x + xv[4 * j + 1] * w.y
               + xv[4 * j + 2] * w.z + xv[4 * j + 3] * w.w;
        }
#pragma unroll
        for (int off = 32; off >= 1; off >>= 1) p += __shfl_xor(p, off, 64);
        logit[e] = p + bg[e];
    }

    int i0 = 0; float v0 = logit[0];
#pragma unroll
    for (int e = 1; e < NUM_EXPERTS; ++e)
        if (logit[e] > v0) { v0 = logit[e]; i0 = e; }
    int i1 = -1; float v1 = -INFINITY;
#pragma unroll
    for (int e = 0; e < NUM_EXPERTS; ++e) {
        if (e == i0) continue;
        if (logit[e] > v1) { v1 = logit[e]; i1 = e; }
    }
    float e1 = expf(v1 - v0);
    float inv = 1.f / (1.f + e1);

    if (lane == 0) {
        eidx[2 * n]     = i0;
        eidx[2 * n + 1] = i1;
        ew[2 * n]       = inv;
        ew[2 * n + 1]   = e1 * inv;
        atomicAdd(&counts[i0], 1);
        atomicAdd(&counts[i1], 1);
    }
}

// ---------------- scan ----------------
__global__ void moe_scan(const int* __restrict__ counts,
                         int* __restrict__ offsets, int* __restrict__ cursor,
                         int* __restrict__ tileBase, int* __restrict__ totalTiles)
{
    int off = 0, tb = 0;
    for (int e = 0; e < NUM_EXPERTS; ++e) {
        offsets[e]  = off;
        cursor[e]   = off;
        tileBase[e] = tb;
        tb  += (counts[e] + TM - 1) / TM;
        off += counts[e];
    }
    offsets[NUM_EXPERTS]  = off;
    tileBase[NUM_EXPERTS] = tb;
    *totalTiles = tb;
}

// ---------------- fill per-expert row lists ----------------
__global__ __launch_bounds__(256) void moe_fill(
    const int* __restrict__ eidx, const float* __restrict__ ew,
    int* __restrict__ cursor, int* __restrict__ rowTok, float* __restrict__ rowW, int N)
{
    int n = blockIdx.x * blockDim.x + threadIdx.x;
    if (n >= N) return;
#pragma unroll
    for (int k = 0; k < TOPK; ++k) {
        int e = eidx[2 * n + k];
        int pos = atomicAdd(&cursor[e], 1);
        rowTok[pos] = n;
        rowW[pos]   = ew[2 * n + k];
    }
}

// ---------------- grouped GEMM, bf16x3 MFMA ----------------
// 128x128 tile, BK=32, 4 waves (2x2), each wave 64x64 = 4x4 frags of 16x16
// LDS layout per plane: [kg][row][8] (kg = k/8) -> ds_read_b128 frags bank-uniform
__global__ __launch_bounds__(256) void moe_gemm_mfma(
    const unsigned short* __restrict__ xhi, const unsigned short* __restrict__ xlo,
    const unsigned short* __restrict__ Whi, const unsigned short* __restrict__ Wlo,
    const float* __restrict__ be,
    const int* __restrict__ offsets, const int* __restrict__ tileBase,
    const int* __restrict__ totalTiles,
    const int* __restrict__ rowTok, const float* __restrict__ rowW,
    float* __restrict__ out)
{
    __shared__ __align__(16) unsigned short Ah[4][128][8];  // 8 KB each
    __shared__ __align__(16) unsigned short Al[4][128][8];
    __shared__ __align__(16) unsigned short Bh[4][128][8];
    __shared__ __align__(16) unsigned short Bl[4][128][8];
    __shared__ int   tokS[TM];
    __shared__ float wS[TM];

    const int tile = blockIdx.x;
    if (tile >= *totalTiles) return;

    int e = 0;
#pragma unroll
    for (int q = 0; q < NUM_EXPERTS; ++q)
        if (tile >= tileBase[q + 1]) e = q + 1;

    const int row0   = offsets[e] + (tile - tileBase[e]) * TM;
    const int rowEnd = offsets[e + 1];
    const int c0     = blockIdx.y * TN;

    const int tid  = threadIdx.x;
    const int lane = tid & 63;
    const int w    = tid >> 6;
    const int wm   = w >> 1, wn = w & 1;

    if (tid < TM) {
        int gr = row0 + tid;
        tokS[tid] = (gr < rowEnd) ? rowTok[gr] : -1;
        wS[tid]   = (gr < rowEnd) ? rowW[gr] : 0.f;
    }
    __syncthreads();

    // per-wave staging role: w0=Ah, w1=Al, w2=Bh, w3=Bl (one 8KB plane each,
    // 8 global_load_lds of 1KB per K-step)
    const unsigned short* srcPlane = (w == 0) ? xhi : (w == 1) ? xlo
                                   : (w == 2) ? Whi : Wlo;
    unsigned short* dstPlane = (w == 0) ? &Ah[0][0][0] : (w == 1) ? &Al[0][0][0]
                             : (w == 2) ? &Bh[0][0][0] : &Bl[0][0][0];
    const unsigned short* base[8];
#pragma unroll
    for (int i = 0; i < 8; ++i) {
        int s  = i * 64 + lane;
        int rc = s & 127;        // row (A) / col (B)
        int kg = s >> 7;         // 0..3
        size_t rowoff;
        if (w < 2) {
            int tok = tokS[rc]; if (tok < 0) tok = 0;
            rowoff = (size_t)tok * D_MODEL;
        } else {
            rowoff = ((size_t)e * D_MODEL + (c0 + rc)) * D_MODEL;
        }
        base[i] = srcPlane + rowoff + kg * 8;
    }

    f32x4 acc[4][4];
#pragma unroll
    for (int m = 0; m < 4; ++m)
#pragma unroll
        for (int n = 0; n < 4; ++n) acc[m][n] = (f32x4){0.f, 0.f, 0.f, 0.f};

    const int kg = lane >> 4;
    const int rA = wm * 64 + (lane & 15);
    const int rB = wn * 64 + (lane & 15);

    for (int t = 0; t < D_MODEL / BK; ++t) {
        const int k0 = t * BK;
#pragma unroll
        for (int i = 0; i < 8; ++i)
            gload_lds16(base[i] + k0, dstPlane + i * 512);
        asm volatile("s_waitcnt vmcnt(0)" ::: "memory");
        __syncthreads();

        short8 ah[4], al[4], bh[4], bl[4];
#pragma unroll
        for (int m = 0; m < 4; ++m) {
            ah[m] = *(const short8*)&Ah[kg][rA + m * 16][0];
            al[m] = *(const short8*)&Al[kg][rA + m * 16][0];
        }
#pragma unroll
        for (int n = 0; n < 4; ++n) {
            bh[n] = *(const short8*)&Bh[kg][rB + n * 16][0];
            bl[n] = *(const short8*)&Bl[kg][rB + n * 16][0];
        }
#pragma unroll
        for (int m = 0; m < 4; ++m)
#pragma unroll
            for (int n = 0; n < 4; ++n) {
                acc[m][n] = __builtin_amdgcn_mfma_f32_16x16x32_bf16(ah[m], bh[n], acc[m][n], 0, 0, 0);
                acc[m][n] = __builtin_amdgcn_mfma_f32_16x16x32_bf16(ah[m], bl[n], acc[m][n], 0, 0, 0);
                acc[m][n] = __builtin_amdgcn_mfma_f32_16x16x32_bf16(al[m], bh[n], acc[m][n], 0, 0, 0);
            }
        __syncthreads();
    }

    // epilogue: C/D layout col=lane&15, row=(lane>>4)*4+reg
    const float* bias = be + (size_t)e * D_MODEL;
#pragma unroll
    for (int m = 0; m < 4; ++m) {
        int rbase = wm * 64 + m * 16 + ((lane >> 4) << 2);
#pragma unroll
        for (int n = 0; n < 4; ++n) {
            int c = c0 + wn * 64 + n * 16 + (lane & 15);
            float bv = bias[c];
            f32x4 a = acc[m][n];
#pragma unroll
            for (int r = 0; r < 4; ++r) {
                int rr = rbase + r;
                int tok = tokS[rr];
                if (tok >= 0)
                    atomicAdd(out + (size_t)tok * D_MODEL + c, wS[rr] * (a[r] + bv));
            }
        }
    }
}

// ---------------- launch ----------------
extern "C" void kernel_launch(void* const* d_in, const int* in_sizes, int n_in,
                              void* d_out, int out_size, void* d_ws, size_t ws_size,
                              hipStream_t stream) {
    const float* x  = (const float*)d_in[0];
    const float* We = (const float*)d_in[1];
    const float* be = (const float*)d_in[2];
    const float* Wg = (const float*)d_in[3];
    const float* bg = (const float*)d_in[4];
    float* out = (float*)d_out;

    const int N = in_sizes[0] / D_MODEL;       // 8192 tokens
    const int R = N * TOPK;                    // 16384 routed rows

    const size_t xPlane = (size_t)N * D_MODEL;              // elems
    const size_t wPlane = (size_t)NUM_EXPERTS * D_MODEL * D_MODEL;

    unsigned short* xhi = (unsigned short*)d_ws;
    unsigned short* xlo = xhi + xPlane;
    unsigned short* Whi = xlo + xPlane;
    unsigned short* Wlo = Whi + wPlane;

    int*   counts     = (int*)(Wlo + wPlane);
    int*   offsets    = counts + 8;
    int*   cursor     = offsets + 9;
    int*   tileBase   = cursor + 8;
    int*   totalTiles = tileBase + 9;
    int*   eidx   = totalTiles + 1;            // [2N]
    float* ew     = (float*)(eidx + R);        // [2N]
    int*   rowTok = (int*)(ew + R);            // [2N]
    float* rowW   = (float*)(rowTok + R);      // [2N]

    hipMemsetAsync(counts, 0, 64, stream);
    hipMemsetAsync(out, 0, (size_t)N * D_MODEL * sizeof(float), stream);

    const int w4 = (int)(wPlane / 4);
    convert_W<<<(w4 + 255) / 256, 256, 0, stream>>>(We, Whi, Wlo, w4);
    gate_convert_x<<<(N + 3) / 4, 256, 0, stream>>>(x, Wg, bg, xhi, xlo,
                                                    eidx, ew, counts, N);
    moe_scan<<<1, 1, 0, stream>>>(counts, offsets, cursor, tileBase, totalTiles);
    moe_fill<<<(N + 255) / 256, 256, 0, stream>>>(eidx, ew, cursor, rowTok, rowW, N);

    const int maxTiles = R / TM + NUM_EXPERTS;
    dim3 grid(maxTiles, D_MODEL / TN);
    moe_gemm_mfma<<<grid, 256, 0, stream>>>(xhi, xlo, Whi, Wlo, be,
                                            offsets, tileBase, totalTiles,
                                            rowTok, rowW, out);
}

// Round 3
// 373.201 us; speedup vs baseline: 2.2559x; 1.9891x over previous
//
#include <hip/hip_runtime.h>
#include <math.h>

#define D_MODEL 1024
#define NUM_EXPERTS 8
#define TOPK 2
#define TM 128
#define TN 128
#define BK 64
#define KP 3072                 // virtual K' = 3 planes x 1024
#define NSTEP (KP / BK)         // 48
#define MAXT (16384 / TM + NUM_EXPERTS)   // 136 padded tiles

typedef __attribute__((ext_vector_type(8))) short short8;
typedef __attribute__((ext_vector_type(4))) float f32x4;
typedef unsigned short ushort_t;

__device__ __forceinline__ unsigned short bf16_rne(float f) {
    unsigned int u = __builtin_bit_cast(unsigned int, f);
    unsigned int r = u + 0x7fffu + ((u >> 16) & 1u);
    return (unsigned short)(r >> 16);
}
__device__ __forceinline__ float bf16f(unsigned short h) {
    unsigned int u = ((unsigned int)h) << 16;
    return __builtin_bit_cast(float, u);
}
__device__ __forceinline__ void gload_lds16(const ushort_t* g, ushort_t* l) {
    __builtin_amdgcn_global_load_lds(
        (const __attribute__((address_space(1))) unsigned int*)g,
        (__attribute__((address_space(3))) unsigned int*)l, 16, 0, 0);
}

// ---- convert We -> Whi/Wlo in staged order [e][ct][kb][kg][col][8] ----
__global__ __launch_bounds__(256) void convert_W_sw(
    const float* __restrict__ W, ushort_t* __restrict__ hi, ushort_t* __restrict__ lo)
{
    int c = blockIdx.x * 256 + threadIdx.x;       // 1,048,576 chunks
    int col = c & 127, kg = (c >> 7) & 7, kb = (c >> 10) & 15;
    int ct = (c >> 14) & 7, e = c >> 17;
    const float4* src = (const float4*)(W + ((size_t)(e * 1024 + ct * 128 + col)) * 1024
                                          + kb * 64 + kg * 8);
    float4 v0 = src[0], v1 = src[1];
    ushort4 h0, l0, h1, l1;
    h0.x = bf16_rne(v0.x); l0.x = bf16_rne(v0.x - bf16f(h0.x));
    h0.y = bf16_rne(v0.y); l0.y = bf16_rne(v0.y - bf16f(h0.y));
    h0.z = bf16_rne(v0.z); l0.z = bf16_rne(v0.z - bf16f(h0.z));
    h0.w = bf16_rne(v0.w); l0.w = bf16_rne(v0.w - bf16f(h0.w));
    h1.x = bf16_rne(v1.x); l1.x = bf16_rne(v1.x - bf16f(h1.x));
    h1.y = bf16_rne(v1.y); l1.y = bf16_rne(v1.y - bf16f(h1.y));
    h1.z = bf16_rne(v1.z); l1.z = bf16_rne(v1.z - bf16f(h1.z));
    h1.w = bf16_rne(v1.w); l1.w = bf16_rne(v1.w - bf16f(h1.w));
    ((ushort4*)(hi + (size_t)c * 8))[0] = h0; ((ushort4*)(hi + (size_t)c * 8))[1] = h1;
    ((ushort4*)(lo + (size_t)c * 8))[0] = l0; ((ushort4*)(lo + (size_t)c * 8))[1] = l1;
}

// ---- gating: one token per wave, no atomics ----
__global__ __launch_bounds__(256) void moe_gate(
    const float* __restrict__ x, const float* __restrict__ Wg,
    const float* __restrict__ bg,
    int* __restrict__ eidx, float* __restrict__ ew, int N)
{
    const int wave = threadIdx.x >> 6, lane = threadIdx.x & 63;
    const int n = blockIdx.x * 4 + wave;
    if (n >= N) return;

    const float4* xr4 = (const float4*)(x + (size_t)n * D_MODEL);
    float xv[16];
#pragma unroll
    for (int j = 0; j < 4; ++j) {
        float4 v = xr4[j * 64 + lane];
        xv[4 * j + 0] = v.x; xv[4 * j + 1] = v.y;
        xv[4 * j + 2] = v.z; xv[4 * j + 3] = v.w;
    }
    float logit[NUM_EXPERTS];
#pragma unroll
    for (int e = 0; e < NUM_EXPERTS; ++e) {
        const float4* wg4 = (const float4*)(Wg + (size_t)e * D_MODEL);
        float p = 0.f;
#pragma unroll
        for (int j = 0; j < 4; ++j) {
            float4 w = wg4[j * 64 + lane];
            p += xv[4 * j + 0] * w.x + xv[4 * j + 1] * w.y
               + xv[4 * j + 2] * w.z + xv[4 * j + 3] * w.w;
        }
#pragma unroll
        for (int off = 32; off >= 1; off >>= 1) p += __shfl_xor(p, off, 64);
        logit[e] = p + bg[e];
    }
    int i0 = 0; float v0 = logit[0];
#pragma unroll
    for (int e = 1; e < NUM_EXPERTS; ++e)
        if (logit[e] > v0) { v0 = logit[e]; i0 = e; }
    int i1 = -1; float v1 = -INFINITY;
#pragma unroll
    for (int e = 0; e < NUM_EXPERTS; ++e) {
        if (e == i0) continue;
        if (logit[e] > v1) { v1 = logit[e]; i1 = e; }
    }
    float e1 = expf(v1 - v0);
    float inv = 1.f / (1.f + e1);
    if (lane == 0) {
        eidx[2 * n]     = i0;
        eidx[2 * n + 1] = i1;
        ew[2 * n]       = inv;
        ew[2 * n + 1]   = e1 * inv;
    }
}

// ---- histogram: block-aggregated, 8 atomics per block ----
__global__ __launch_bounds__(256) void moe_count(
    const int* __restrict__ eidx, int* __restrict__ counts)
{
    __shared__ int h[NUM_EXPERTS];
    if (threadIdx.x < NUM_EXPERTS) h[threadIdx.x] = 0;
    __syncthreads();
    int e = eidx[blockIdx.x * 256 + threadIdx.x];
    atomicAdd(&h[e], 1);
    __syncthreads();
    if (threadIdx.x < NUM_EXPERTS) atomicAdd(&counts[threadIdx.x], h[threadIdx.x]);
}

// ---- scan ----
__global__ void moe_scan(const int* __restrict__ counts,
                         int* __restrict__ tileBase, int* __restrict__ cursorP,
                         int* __restrict__ totalTiles)
{
    int tb = 0;
    for (int e = 0; e < NUM_EXPERTS; ++e) {
        tileBase[e] = tb;
        cursorP[e]  = tb * TM;
        tb += (counts[e] + TM - 1) / TM;
    }
    tileBase[NUM_EXPERTS] = tb;
    *totalTiles = tb;
}

// ---- fill padded row lists: LDS ranks + 8 global atomics per block ----
__global__ __launch_bounds__(512) void moe_fill_pad(
    const int* __restrict__ eidx, const float* __restrict__ ew,
    int* __restrict__ cursorP, int* __restrict__ rowTokP, float* __restrict__ rowWP)
{
    __shared__ int lh[NUM_EXPERTS], base[NUM_EXPERTS];
    if (threadIdx.x < NUM_EXPERTS) lh[threadIdx.x] = 0;
    __syncthreads();
    int i = blockIdx.x * 512 + threadIdx.x;       // 32 blocks x 512 = 16384 entries
    int e = eidx[i];
    int rank = atomicAdd(&lh[e], 1);
    __syncthreads();
    if (threadIdx.x < NUM_EXPERTS)
        base[threadIdx.x] = atomicAdd(&cursorP[threadIdx.x], lh[threadIdx.x]);
    __syncthreads();
    int pr = base[e] + rank;
    rowTokP[pr] = i >> 1;
    rowWP[pr]   = ew[i];
}

// ---- pack gathered A rows into staged order [rt][kb][kg][row][8], hi/lo ----
__global__ __launch_bounds__(256) void moe_packA(
    const float* __restrict__ x, const int* __restrict__ rowTokP,
    const int* __restrict__ totalTiles,
    ushort_t* __restrict__ Ah, ushort_t* __restrict__ Al)
{
    int c = blockIdx.x * 256 + threadIdx.x;       // MAXT*16384 chunks
    int row = c & 127, kg = (c >> 7) & 7, kb = (c >> 10) & 15, rt = c >> 14;
    if (rt >= *totalTiles) return;
    int tok = rowTokP[rt * 128 + row];
    if (tok < 0) return;                           // pad row: poison is masked later
    const float4* src = (const float4*)(x + (size_t)tok * D_MODEL + kb * 64 + kg * 8);
    float4 v0 = src[0], v1 = src[1];
    ushort4 h0, l0, h1, l1;
    h0.x = bf16_rne(v0.x); l0.x = bf16_rne(v0.x - bf16f(h0.x));
    h0.y = bf16_rne(v0.y); l0.y = bf16_rne(v0.y - bf16f(h0.y));
    h0.z = bf16_rne(v0.z); l0.z = bf16_rne(v0.z - bf16f(h0.z));
    h0.w = bf16_rne(v0.w); l0.w = bf16_rne(v0.w - bf16f(h0.w));
    h1.x = bf16_rne(v1.x); l1.x = bf16_rne(v1.x - bf16f(h1.x));
    h1.y = bf16_rne(v1.y); l1.y = bf16_rne(v1.y - bf16f(h1.y));
    h1.z = bf16_rne(v1.z); l1.z = bf16_rne(v1.z - bf16f(h1.z));
    h1.w = bf16_rne(v1.w); l1.w = bf16_rne(v1.w - bf16f(h1.w));
    ((ushort4*)(Ah + (size_t)c * 8))[0] = h0; ((ushort4*)(Ah + (size_t)c * 8))[1] = h1;
    ((ushort4*)(Al + (size_t)c * 8))[0] = l0; ((ushort4*)(Al + (size_t)c * 8))[1] = l1;
}

// ---- grouped GEMM, virtual K-concat [Ah|Al|Ah]x[Bh|Bh|Bl], 2-phase prefetch ----
__global__ __launch_bounds__(256) void moe_gemm_v3(
    const ushort_t* __restrict__ Ah, const ushort_t* __restrict__ Al,
    const ushort_t* __restrict__ Bh, const ushort_t* __restrict__ Bl,
    const float* __restrict__ be,
    const int* __restrict__ tileBase, const int* __restrict__ totalTiles,
    const int* __restrict__ rowTokP, const float* __restrict__ rowWP,
    float* __restrict__ out)
{
    __shared__ __align__(16) ushort_t As[2][8192];   // [8 kg][128 row][8]
    __shared__ __align__(16) ushort_t Bs[2][8192];
    __shared__ int   tokS[TM];
    __shared__ float wS[TM];

    const int tile = blockIdx.x;
    if (tile >= *totalTiles) return;

    int e = 0;
#pragma unroll
    for (int q = 0; q < NUM_EXPERTS; ++q)
        if (tile >= tileBase[q + 1]) e = q + 1;

    const int tid  = threadIdx.x;
    const int lane = tid & 63;
    const int w    = tid >> 6;
    const int wm   = w >> 1, wn = w & 1;
    const int half = (w & 1) * 4096;

    if (tid < TM) {
        tokS[tid] = rowTokP[tile * TM + tid];
        wS[tid]   = rowWP[tile * TM + tid];
    }

    const size_t aTile = (size_t)tile * 131072;                    // 16 kb * 8192
    const size_t bTile = ((size_t)e * 8 + blockIdx.y) * 131072;
    const bool stageA = (w < 2);
    ushort_t* dst0 = (stageA ? As[0] : Bs[0]) + half;
    ushort_t* dst1 = (stageA ? As[1] : Bs[1]) + half;

    // stage K-step t into buffer dst: 8 x 1KB linear global_load_lds
#define STAGE(DST, T) do {                                                        \
        int kb_ = (T) & 15;                                                       \
        const ushort_t* src_;                                                     \
        if (stageA) src_ = (((T) >= 16 && (T) < 32) ? Al : Ah) + aTile            \
                           + kb_ * 8192 + half;                                   \
        else        src_ = (((T) < 32) ? Bh : Bl) + bTile + kb_ * 8192 + half;    \
        _Pragma("unroll")                                                         \
        for (int i_ = 0; i_ < 8; ++i_)                                            \
            gload_lds16(src_ + i_ * 512 + lane * 8, (DST) + i_ * 512);            \
    } while (0)

    f32x4 acc[4][4];
#pragma unroll
    for (int m = 0; m < 4; ++m)
#pragma unroll
        for (int n = 0; n < 4; ++n) acc[m][n] = (f32x4){0.f, 0.f, 0.f, 0.f};

    const int kg = lane >> 4;
    const int rA = wm * 64 + (lane & 15);
    const int rB = wn * 64 + (lane & 15);

#define COMPUTE(BUF) do {                                                         \
        _Pragma("unroll")                                                         \
        for (int c_ = 0; c_ < 2; ++c_) {                                          \
            short8 af[4], bf[4];                                                  \
            _Pragma("unroll")                                                     \
            for (int m_ = 0; m_ < 4; ++m_)                                        \
                af[m_] = *(const short8*)&As[BUF][((c_ * 4 + kg) * 128 + rA + m_ * 16) * 8]; \
            _Pragma("unroll")                                                     \
            for (int n_ = 0; n_ < 4; ++n_)                                        \
                bf[n_] = *(const short8*)&Bs[BUF][((c_ * 4 + kg) * 128 + rB + n_ * 16) * 8]; \
            _Pragma("unroll")                                                     \
            for (int m_ = 0; m_ < 4; ++m_)                                        \
                _Pragma("unroll")                                                 \
                for (int n_ = 0; n_ < 4; ++n_)                                    \
                    acc[m_][n_] = __builtin_amdgcn_mfma_f32_16x16x32_bf16(        \
                        af[m_], bf[n_], acc[m_][n_], 0, 0, 0);                    \
        }                                                                         \
    } while (0)

    STAGE(dst0, 0);
    __syncthreads();                 // drains vmcnt(0): buf0 ready; tokS visible
    for (int t = 0; t < NSTEP; t += 2) {
        if (t + 1 < NSTEP) STAGE(dst1, t + 1);
        COMPUTE(0);
        __syncthreads();             // drains stage(t+1); LDS reads of buf0 done
        if (t + 2 < NSTEP) STAGE(dst0, t + 2);
        COMPUTE(1);
        __syncthreads();
    }

    // epilogue: C/D layout col=lane&15, row=(lane>>4)*4+reg
    const float* bias = be + (size_t)e * D_MODEL;
    const int c0 = blockIdx.y * TN;
#pragma unroll
    for (int m = 0; m < 4; ++m) {
        int rbase = wm * 64 + m * 16 + ((lane >> 4) << 2);
#pragma unroll
        for (int n = 0; n < 4; ++n) {
            int c = c0 + wn * 64 + n * 16 + (lane & 15);
            float bv = bias[c];
            f32x4 a = acc[m][n];
#pragma unroll
            for (int r = 0; r < 4; ++r) {
                int rr = rbase + r;
                int tok = tokS[rr];
                if (tok >= 0)
                    atomicAdd(out + (size_t)tok * D_MODEL + c, wS[rr] * (a[r] + bv));
            }
        }
    }
#undef STAGE
#undef COMPUTE
}

// ---- launch ----
extern "C" void kernel_launch(void* const* d_in, const int* in_sizes, int n_in,
                              void* d_out, int out_size, void* d_ws, size_t ws_size,
                              hipStream_t stream) {
    const float* x  = (const float*)d_in[0];
    const float* We = (const float*)d_in[1];
    const float* be = (const float*)d_in[2];
    const float* Wg = (const float*)d_in[3];
    const float* bg = (const float*)d_in[4];
    float* out = (float*)d_out;

    const int N = in_sizes[0] / D_MODEL;           // 8192 tokens
    const int R = N * TOPK;                        // 16384 routed rows

    const size_t aPlane = (size_t)MAXT * 131072;   // elems (35.7 MB @2B)
    const size_t bPlane = (size_t)NUM_EXPERTS * D_MODEL * D_MODEL;  // 16.8 MB

    ushort_t* Ah = (ushort_t*)d_ws;
    ushort_t* Al = Ah + aPlane;
    ushort_t* Bh = Al + aPlane;
    ushort_t* Bl = Bh + bPlane;
    int*   counts     = (int*)(Bl + bPlane);
    int*   tileBase   = counts + 8;                // 9
    int*   cursorP    = tileBase + 9;              // 8
    int*   totalTiles = cursorP + 8;               // 1
    int*   eidx       = totalTiles + 1;            // [2N]
    float* ew         = (float*)(eidx + R);        // [2N]
    int*   rowTokP    = (int*)(ew + R);            // [MAXT*128]
    float* rowWP      = (float*)(rowTokP + MAXT * TM);

    const size_t need = (size_t)((char*)(rowWP + MAXT * TM) - (char*)d_ws);
    if (ws_size < need) return;                    // fail loudly via validation

    hipMemsetAsync(counts, 0, 32, stream);
    hipMemsetAsync(rowTokP, 0xFF, MAXT * TM * sizeof(int), stream);  // pad rows = -1
    hipMemsetAsync(out, 0, (size_t)N * D_MODEL * sizeof(float), stream);

    convert_W_sw<<<4096, 256, 0, stream>>>(We, Bh, Bl);
    moe_gate<<<(N + 3) / 4, 256, 0, stream>>>(x, Wg, bg, eidx, ew, N);
    moe_count<<<R / 256, 256, 0, stream>>>(eidx, counts);
    moe_scan<<<1, 1, 0, stream>>>(counts, tileBase, cursorP, totalTiles);
    moe_fill_pad<<<R / 512, 512, 0, stream>>>(eidx, ew, cursorP, rowTokP, rowWP);
    moe_packA<<<MAXT * 16384 / 256, 256, 0, stream>>>(x, rowTokP, totalTiles, Ah, Al);

    dim3 grid(MAXT, D_MODEL / TN);
    moe_gemm_v3<<<grid, 256, 0, stream>>>(Ah, Al, Bh, Bl, be,
                                          tileBase, totalTiles, rowTokP, rowWP, out);
}